// Round 3
// baseline (808.607 us; speedup 1.0000x reference)
//
#include <hip/hip_runtime.h>
#include <hip/hip_bf16.h>

#define N_NODES 50000
#define IN_DIM 768
#define HID 128
#define NCLS 32

// ---------------- edge conversion (handles int32 or int64 edge_index) ----------
__global__ void convert_edges(const int* __restrict__ raw, int E,
                              int* __restrict__ src, int* __restrict__ dst) {
    // int64 detection: hi-words of first 4 src values are all zero
    bool is64 = (raw[1] == 0 && raw[3] == 0 && raw[5] == 0 && raw[7] == 0);
    int e = blockIdx.x * blockDim.x + threadIdx.x;
    if (e < E) {
        if (is64) {
            src[e] = raw[2 * e];
            dst[e] = raw[2 * (E + e)];
        } else {
            src[e] = raw[e];
            dst[e] = raw[E + e];
        }
    }
}

__global__ void count_deg(const int* __restrict__ dst, int E, int* __restrict__ deg) {
    int e = blockIdx.x * blockDim.x + threadIdx.x;
    if (e < E) atomicAdd(&deg[dst[e]], 1);
}

__global__ void compute_dinv(const int* __restrict__ deg, float* __restrict__ dinv, int n) {
    int i = blockIdx.x * blockDim.x + threadIdx.x;
    if (i < n) dinv[i] = rsqrtf((float)(deg[i] + 1));  // +1 = self-loop
}

// single-block exclusive scan of cnt[0..n) -> row_ptr[0..n]
__global__ __launch_bounds__(1024) void scan_rowptr(const int* __restrict__ cnt,
                                                    int* __restrict__ row_ptr, int n) {
    __shared__ int part[1024];
    int t = threadIdx.x;
    int chunk = (n + 1023) >> 10;
    int b = t * chunk;
    int e = min(b + chunk, n);
    int s = 0;
    for (int i = b; i < e; ++i) s += cnt[i];
    part[t] = s;
    __syncthreads();
    for (int off = 1; off < 1024; off <<= 1) {
        int v = 0;
        if (t >= off) v = part[t - off];
        __syncthreads();
        part[t] += v;
        __syncthreads();
    }
    int base = (t == 0) ? 0 : part[t - 1];
    for (int i = b; i < e; ++i) { row_ptr[i] = base; base += cnt[i]; }
    if (t == 1023) row_ptr[n] = part[1023];
}

__global__ void scatter_csr(const int* __restrict__ src, const int* __restrict__ dst, int E,
                            const int* __restrict__ row_ptr, int* __restrict__ fill,
                            int* __restrict__ csr_src) {
    int e = blockIdx.x * blockDim.x + threadIdx.x;
    if (e < E) {
        int d = dst[e];
        int pos = row_ptr[d] + atomicAdd(&fill[d], 1);
        csr_src[pos] = src[e];
    }
}

// ---------------- GEMM: C[M,128] = A[M,K] @ B[K,128], f32 VALU --------------
__global__ __launch_bounds__(256) void gemm_n128(const float* __restrict__ A,
                                                 const float* __restrict__ B,
                                                 float* __restrict__ C, int M, int K) {
    __shared__ float As[64][33];
    __shared__ float Bs[32][128];
    int tid = threadIdx.x;
    int tx = tid & 15;   // col group: cols tx*8 .. +8
    int ty = tid >> 4;   // row group: rows ty*4 .. +4
    int row0 = blockIdx.x * 64;
    float acc[4][8] = {};
    for (int kk = 0; kk < K; kk += 32) {
        // stage A tile: 64 x 32 (512 float4 loads, coalesced)
#pragma unroll
        for (int l = 0; l < 2; ++l) {
            int idx = l * 256 + tid;
            int r = idx >> 3, c4 = idx & 7;
            float4 v = make_float4(0.f, 0.f, 0.f, 0.f);
            int gr = row0 + r;
            if (gr < M) v = *(const float4*)&A[(size_t)gr * K + kk + c4 * 4];
            As[r][c4 * 4 + 0] = v.x; As[r][c4 * 4 + 1] = v.y;
            As[r][c4 * 4 + 2] = v.z; As[r][c4 * 4 + 3] = v.w;
        }
        // stage B tile: 32 x 128
#pragma unroll
        for (int l = 0; l < 4; ++l) {
            int idx = l * 256 + tid;
            int r = idx >> 5, c4 = idx & 31;
            float4 v = *(const float4*)&B[(size_t)(kk + r) * 128 + c4 * 4];
            *(float4*)&Bs[r][c4 * 4] = v;
        }
        __syncthreads();
#pragma unroll
        for (int k2 = 0; k2 < 32; ++k2) {
            float a[4], b[8];
#pragma unroll
            for (int i = 0; i < 4; ++i) a[i] = As[ty * 4 + i][k2];
#pragma unroll
            for (int j = 0; j < 8; ++j) b[j] = Bs[k2][tx * 8 + j];
#pragma unroll
            for (int i = 0; i < 4; ++i)
#pragma unroll
                for (int j = 0; j < 8; ++j) acc[i][j] += a[i] * b[j];
        }
        __syncthreads();
    }
    for (int i = 0; i < 4; ++i) {
        int gr = row0 + ty * 4 + i;
        if (gr < M) {
            *(float4*)&C[(size_t)gr * 128 + tx * 8] =
                make_float4(acc[i][0], acc[i][1], acc[i][2], acc[i][3]);
            *(float4*)&C[(size_t)gr * 128 + tx * 8 + 4] =
                make_float4(acc[i][4], acc[i][5], acc[i][6], acc[i][7]);
        }
    }
}

// ---------------- aggregation: out[i] = relu(b + sum_j norm_ij * h[j]) -------
__global__ __launch_bounds__(128) void aggregate(const float* __restrict__ hlin,
                                                 const int* __restrict__ row_ptr,
                                                 const int* __restrict__ csr_src,
                                                 const float* __restrict__ dinv,
                                                 const float* __restrict__ bias,
                                                 float* __restrict__ out, int n) {
    int i = blockIdx.x;
    int f = threadIdx.x;
    float di = dinv[i];
    float acc = di * di * hlin[(size_t)i * HID + f];  // self-loop
    int b = row_ptr[i], e = row_ptr[i + 1];
    for (int p = b; p < e; ++p) {
        int s = csr_src[p];
        float nrm = di * dinv[s];
        acc += nrm * hlin[(size_t)s * HID + f];
    }
    out[(size_t)i * HID + f] = fmaxf(acc + bias[f], 0.0f);
}

// ---------------- final FC: out[N,32] = h[N,128] @ Wfc[128,32] + bfc ---------
__global__ __launch_bounds__(256) void fc_out(const float* __restrict__ h,
                                              const float* __restrict__ W,
                                              const float* __restrict__ b,
                                              float* __restrict__ out, int n) {
    __shared__ float Ws[HID * NCLS];
    __shared__ float Hs[8][HID];
    int tid = threadIdx.x;
#pragma unroll
    for (int l = 0; l < 16; ++l) Ws[l * 256 + tid] = W[l * 256 + tid];
    int row0 = blockIdx.x * 8;
#pragma unroll
    for (int l = 0; l < 4; ++l) {
        int idx = l * 256 + tid;
        int r = idx >> 7, c = idx & 127;
        int gr = row0 + r;
        Hs[r][c] = (gr < n) ? h[(size_t)gr * HID + c] : 0.f;
    }
    __syncthreads();
    int r = tid >> 5, c = tid & 31;
    float acc = b[c];
#pragma unroll
    for (int k = 0; k < HID; ++k) acc += Hs[r][k] * Ws[k * NCLS + c];
    int gr = row0 + r;
    if (gr < n) out[(size_t)gr * NCLS + c] = acc;
}

extern "C" void kernel_launch(void* const* d_in, const int* in_sizes, int n_in,
                              void* d_out, int out_size, void* d_ws, size_t ws_size,
                              hipStream_t stream) {
    const float* x   = (const float*)d_in[0];
    const int*   eid = (const int*)d_in[1];
    const float* W1  = (const float*)d_in[2];
    const float* b1  = (const float*)d_in[3];
    const float* W2  = (const float*)d_in[4];
    const float* b2  = (const float*)d_in[5];
    const float* Wfc = (const float*)d_in[6];
    const float* bfc = (const float*)d_in[7];
    float* out = (float*)d_out;

    const int N = N_NODES;
    const int E = in_sizes[1] / 2;

    // workspace carve (256B aligned)
    auto align = [](size_t v) { return (v + 255) & ~(size_t)255; };
    char* w = (char*)d_ws;
    size_t off = 0;
    int* src = (int*)(w + off);          off = align(off + (size_t)E * 4);
    int* dst = (int*)(w + off);          off = align(off + (size_t)E * 4);
    int* deg = (int*)(w + off);          off += (size_t)N * 4;   // deg+fill contiguous
    int* fill = (int*)(w + off);         off = align(off + (size_t)N * 4);
    int* rowp = (int*)(w + off);         off = align(off + (size_t)(N + 1) * 4);
    float* dinv = (float*)(w + off);     off = align(off + (size_t)N * 4);
    int* csr = (int*)(w + off);          off = align(off + (size_t)E * 4);
    float* bufA = (float*)(w + off);     off = align(off + (size_t)N * HID * 4);
    float* bufB = (float*)(w + off);     off = align(off + (size_t)N * HID * 4);

    int eb = (E + 255) / 256;
    convert_edges<<<eb, 256, 0, stream>>>(eid, E, src, dst);
    hipMemsetAsync(deg, 0, (size_t)2 * N * 4, stream);  // deg + fill
    count_deg<<<eb, 256, 0, stream>>>(dst, E, deg);
    compute_dinv<<<(N + 255) / 256, 256, 0, stream>>>(deg, dinv, N);
    scan_rowptr<<<1, 1024, 0, stream>>>(deg, rowp, N);
    scatter_csr<<<eb, 256, 0, stream>>>(src, dst, E, rowp, fill, csr);

    int gb = (N + 63) / 64;
    gemm_n128<<<gb, 256, 0, stream>>>(x, W1, bufA, N, IN_DIM);
    aggregate<<<N, 128, 0, stream>>>(bufA, rowp, csr, dinv, b1, bufB, N);
    gemm_n128<<<gb, 256, 0, stream>>>(bufB, W2, bufA, N, HID);
    aggregate<<<N, 128, 0, stream>>>(bufA, rowp, csr, dinv, b2, bufB, N);
    fc_out<<<(N + 7) / 8, 256, 0, stream>>>(bufB, Wfc, bfc, out, N);
}

// Round 5
// 555.563 us; speedup vs baseline: 1.4555x; 1.4555x over previous
//
#include <hip/hip_runtime.h>
#include <hip/hip_bf16.h>

#define N_NODES 50000
#define IN_DIM 768
#define HID 128
#define NCLS 32

typedef __attribute__((ext_vector_type(8))) short bf16x8;
typedef __attribute__((ext_vector_type(4))) float f32x4;
typedef __attribute__((ext_vector_type(4))) unsigned short u16x4;

__device__ inline void split_bf16(float x, unsigned short& hi, unsigned short& lo) {
    unsigned int u = __float_as_uint(x);
    hi = (unsigned short)(u >> 16);
    float r = x - __uint_as_float(u & 0xFFFF0000u);
    lo = (unsigned short)(__float_as_uint(r) >> 16);
}

// ---------------- edge conversion + degree count (int32 or int64 input) -------
__global__ void convert_count(const int* __restrict__ raw, int E,
                              int* __restrict__ src, int* __restrict__ dst,
                              int* __restrict__ deg) {
    bool is64 = (raw[1] == 0 && raw[3] == 0 && raw[5] == 0 && raw[7] == 0);
    int e = blockIdx.x * blockDim.x + threadIdx.x;
    if (e < E) {
        int s, d;
        if (is64) { s = raw[2 * e]; d = raw[2 * (E + e)]; }
        else      { s = raw[e];     d = raw[E + e]; }
        src[e] = s; dst[e] = d;
        atomicAdd(&deg[d], 1);
    }
}

__global__ void compute_dinv(const int* __restrict__ deg, float* __restrict__ dinv, int n) {
    int i = blockIdx.x * blockDim.x + threadIdx.x;
    if (i < n) dinv[i] = rsqrtf((float)(deg[i] + 1));  // +1 = self-loop
}

// ---------------- hierarchical exclusive scan (3 kernels) --------------------
__global__ __launch_bounds__(256) void scan_blk_sum(const int* __restrict__ cnt, int n,
                                                    int* __restrict__ bsum) {
    __shared__ int sm[256];
    int gid = blockIdx.x * 256 + threadIdx.x;
    sm[threadIdx.x] = (gid < n) ? cnt[gid] : 0;
    __syncthreads();
    for (int o = 128; o > 0; o >>= 1) {
        if (threadIdx.x < o) sm[threadIdx.x] += sm[threadIdx.x + o];
        __syncthreads();
    }
    if (threadIdx.x == 0) bsum[blockIdx.x] = sm[0];
}

__global__ __launch_bounds__(256) void scan_offsets(int* __restrict__ bsum, int nb,
                                                    int* __restrict__ rowp, int n, int Etot) {
    __shared__ int sm[256];
    int t = threadIdx.x;
    sm[t] = (t < nb) ? bsum[t] : 0;
    __syncthreads();
    for (int o = 1; o < 256; o <<= 1) {
        int v = (t >= o) ? sm[t - o] : 0;
        __syncthreads();
        sm[t] += v;
        __syncthreads();
    }
    if (t < nb) bsum[t] = (t == 0) ? 0 : sm[t - 1];
    if (t == 0) rowp[n] = Etot;
}

__global__ __launch_bounds__(256) void scan_final(const int* __restrict__ cnt, int n,
                                                  const int* __restrict__ bsum,
                                                  int* __restrict__ rowp) {
    __shared__ int sm[256];
    int t = threadIdx.x;
    int gid = blockIdx.x * 256 + t;
    int v = (gid < n) ? cnt[gid] : 0;
    sm[t] = v;
    __syncthreads();
    for (int o = 1; o < 256; o <<= 1) {
        int u = (t >= o) ? sm[t - o] : 0;
        __syncthreads();
        sm[t] += u;
        __syncthreads();
    }
    if (gid < n) rowp[gid] = bsum[blockIdx.x] + sm[t] - v;  // exclusive
}

__global__ void scatter_csr(const int* __restrict__ src, const int* __restrict__ dst, int E,
                            const int* __restrict__ row_ptr, int* __restrict__ fill,
                            int* __restrict__ csr_src) {
    int e = blockIdx.x * blockDim.x + threadIdx.x;
    if (e < E) {
        int d = dst[e];
        int pos = row_ptr[d] + atomicAdd(&fill[d], 1);
        csr_src[pos] = src[e];
    }
}

// ---------------- weight pre-split: B[K][128] f32 -> BhT/BlT [128][K] bf16 ----
__global__ void split_w(const float* __restrict__ B, int K,
                        unsigned short* __restrict__ hT, unsigned short* __restrict__ lT) {
    int idx = blockIdx.x * 256 + threadIdx.x;
    if (idx >= K * 128) return;
    int k = idx >> 7, c = idx & 127;
    unsigned short h, l;
    split_bf16(B[idx], h, l);
    hT[c * K + k] = h;
    lT[c * K + k] = l;
}

// ---------------- split-bf16 MFMA GEMM: C[M,128] = A[M,K] @ B[K,128] ---------
// A f32 staged to LDS with hi/lo split; B pre-split transposed bf16 in global.
template <int K>
__global__ __launch_bounds__(256) void gemm_mfma(const float* __restrict__ A,
                                                 const unsigned short* __restrict__ BhT,
                                                 const unsigned short* __restrict__ BlT,
                                                 float* __restrict__ C, int M) {
    __shared__ unsigned short Ah[64][40];  // 32 + 8 pad
    __shared__ unsigned short Al[64][40];
    int tid = threadIdx.x;
    int wid = tid >> 6, lane = tid & 63;
    int wr = wid >> 1, wc = wid & 1;      // wave grid 2x2: rows wr*32, cols wc*64
    int row0 = blockIdx.x * 64;
    int lrow = lane & 15, lk = (lane >> 4) * 8;

    f32x4 acc[2][4] = {};
    for (int kk = 0; kk < K; kk += 32) {
        // stage A 64x32 f32 -> split bf16 LDS
#pragma unroll
        for (int l = 0; l < 2; ++l) {
            int idx = l * 256 + tid;
            int r = idx >> 3, c4 = (idx & 7) * 4;
            float4 v = make_float4(0.f, 0.f, 0.f, 0.f);
            int gr = row0 + r;
            if (gr < M) v = *(const float4*)&A[(size_t)gr * K + kk + c4];
            u16x4 h, lo;
            split_bf16(v.x, ((unsigned short*)&h)[0], ((unsigned short*)&lo)[0]);
            split_bf16(v.y, ((unsigned short*)&h)[1], ((unsigned short*)&lo)[1]);
            split_bf16(v.z, ((unsigned short*)&h)[2], ((unsigned short*)&lo)[2]);
            split_bf16(v.w, ((unsigned short*)&h)[3], ((unsigned short*)&lo)[3]);
            *(u16x4*)&Ah[r][c4] = h;
            *(u16x4*)&Al[r][c4] = lo;
        }
        __syncthreads();
        // A fragments from LDS
        bf16x8 ah[2], al[2];
#pragma unroll
        for (int m = 0; m < 2; ++m) {
            int r = wr * 32 + m * 16 + lrow;
            ah[m] = *(const bf16x8*)&Ah[r][lk];
            al[m] = *(const bf16x8*)&Al[r][lk];
        }
        // B fragments straight from global (L2-hot)
        bf16x8 bh[4], bl[4];
#pragma unroll
        for (int n = 0; n < 4; ++n) {
            int col = wc * 64 + n * 16 + lrow;
            size_t off = (size_t)col * K + kk + lk;
            bh[n] = *(const bf16x8*)&BhT[off];
            bl[n] = *(const bf16x8*)&BlT[off];
        }
#pragma unroll
        for (int m = 0; m < 2; ++m)
#pragma unroll
            for (int n = 0; n < 4; ++n) {
                acc[m][n] = __builtin_amdgcn_mfma_f32_16x16x32_bf16(ah[m], bh[n], acc[m][n], 0, 0, 0);
                acc[m][n] = __builtin_amdgcn_mfma_f32_16x16x32_bf16(al[m], bh[n], acc[m][n], 0, 0, 0);
                acc[m][n] = __builtin_amdgcn_mfma_f32_16x16x32_bf16(ah[m], bl[n], acc[m][n], 0, 0, 0);
            }
        __syncthreads();
    }
    // epilogue: C/D layout col=lane&15, row=(lane>>4)*4+j
#pragma unroll
    for (int m = 0; m < 2; ++m) {
        int rbase = row0 + wr * 32 + m * 16 + (lane >> 4) * 4;
#pragma unroll
        for (int n = 0; n < 4; ++n) {
            int col = wc * 64 + n * 16 + lrow;
#pragma unroll
            for (int j = 0; j < 4; ++j) {
                int r = rbase + j;
                if (r < M) C[(size_t)r * 128 + col] = acc[m][n][j];
            }
        }
    }
}

// ---------------- aggregation: wave-per-node, float2/lane, unroll-4 ----------
__global__ __launch_bounds__(256) void aggregate2(const float* __restrict__ hlin,
                                                  const int* __restrict__ rowp,
                                                  const int* __restrict__ csr,
                                                  const float* __restrict__ dinv,
                                                  const float* __restrict__ bias,
                                                  float* __restrict__ out, int n) {
    int wid = threadIdx.x >> 6, lane = threadIdx.x & 63;
    int i = blockIdx.x * 4 + wid;
    if (i >= n) return;
    const float2* h2 = (const float2*)hlin;
    float di = dinv[i];
    float2 self = h2[(size_t)i * 64 + lane];
    float2 acc;
    acc.x = di * di * self.x;
    acc.y = di * di * self.y;
    int b = rowp[i], e = rowp[i + 1];
    int p = b;
    for (; p + 4 <= e; p += 4) {
        int s0 = csr[p], s1 = csr[p + 1], s2 = csr[p + 2], s3 = csr[p + 3];
        float n0 = dinv[s0] * di, n1 = dinv[s1] * di, n2 = dinv[s2] * di, n3 = dinv[s3] * di;
        float2 v0 = h2[(size_t)s0 * 64 + lane];
        float2 v1 = h2[(size_t)s1 * 64 + lane];
        float2 v2 = h2[(size_t)s2 * 64 + lane];
        float2 v3 = h2[(size_t)s3 * 64 + lane];
        acc.x += n0 * v0.x + n1 * v1.x + n2 * v2.x + n3 * v3.x;
        acc.y += n0 * v0.y + n1 * v1.y + n2 * v2.y + n3 * v3.y;
    }
    for (; p < e; ++p) {
        int s = csr[p];
        float nn = dinv[s] * di;
        float2 v = h2[(size_t)s * 64 + lane];
        acc.x += nn * v.x;
        acc.y += nn * v.y;
    }
    float2 bb = ((const float2*)bias)[lane];
    float2 o;
    o.x = fmaxf(acc.x + bb.x, 0.f);
    o.y = fmaxf(acc.y + bb.y, 0.f);
    ((float2*)out)[(size_t)i * 64 + lane] = o;
}

// ---------------- final FC: out[N,32] = h[N,128] @ Wfc[128,32] + bfc ---------
__global__ __launch_bounds__(256) void fc_out(const float* __restrict__ h,
                                              const float* __restrict__ W,
                                              const float* __restrict__ b,
                                              float* __restrict__ out, int n) {
    __shared__ float Ws[HID * NCLS];
    __shared__ float Hs[8][HID];
    int tid = threadIdx.x;
#pragma unroll
    for (int l = 0; l < 16; ++l) Ws[l * 256 + tid] = W[l * 256 + tid];
    int row0 = blockIdx.x * 8;
#pragma unroll
    for (int l = 0; l < 4; ++l) {
        int idx = l * 256 + tid;
        int r = idx >> 7, c = idx & 127;
        int gr = row0 + r;
        Hs[r][c] = (gr < n) ? h[(size_t)gr * HID + c] : 0.f;
    }
    __syncthreads();
    int r = tid >> 5, c = tid & 31;
    float acc = b[c];
#pragma unroll
    for (int k = 0; k < HID; ++k) acc += Hs[r][k] * Ws[k * NCLS + c];
    int gr = row0 + r;
    if (gr < n) out[(size_t)gr * NCLS + c] = acc;
}

extern "C" void kernel_launch(void* const* d_in, const int* in_sizes, int n_in,
                              void* d_out, int out_size, void* d_ws, size_t ws_size,
                              hipStream_t stream) {
    const float* x   = (const float*)d_in[0];
    const int*   eid = (const int*)d_in[1];
    const float* W1  = (const float*)d_in[2];
    const float* b1  = (const float*)d_in[3];
    const float* W2  = (const float*)d_in[4];
    const float* b2  = (const float*)d_in[5];
    const float* Wfc = (const float*)d_in[6];
    const float* bfc = (const float*)d_in[7];
    float* out = (float*)d_out;

    const int N = N_NODES;
    const int E = in_sizes[1] / 2;
    const int NB1 = (N + 255) / 256;  // 196

    auto align = [](size_t v) { return (v + 255) & ~(size_t)255; };
    char* w = (char*)d_ws;
    size_t off = 0;
    int* src = (int*)(w + off);            off = align(off + (size_t)E * 4);
    int* dst = (int*)(w + off);            off = align(off + (size_t)E * 4);
    int* deg = (int*)(w + off);            off += (size_t)N * 4;  // deg+fill contiguous (one memset)
    int* fill = (int*)(w + off);           off = align(off + (size_t)N * 4);
    int* rowp = (int*)(w + off);           off = align(off + (size_t)(N + 1) * 4);
    float* dinv = (float*)(w + off);       off = align(off + (size_t)N * 4);
    int* csr = (int*)(w + off);            off = align(off + (size_t)E * 4);
    int* bsum = (int*)(w + off);           off = align(off + (size_t)NB1 * 4);
    unsigned short* W1hT = (unsigned short*)(w + off); off = align(off + (size_t)128 * IN_DIM * 2);
    unsigned short* W1lT = (unsigned short*)(w + off); off = align(off + (size_t)128 * IN_DIM * 2);
    unsigned short* W2hT = (unsigned short*)(w + off); off = align(off + (size_t)128 * HID * 2);
    unsigned short* W2lT = (unsigned short*)(w + off); off = align(off + (size_t)128 * HID * 2);
    float* bufA = (float*)(w + off);       off = align(off + (size_t)N * HID * 4);
    float* bufB = (float*)(w + off);       off = align(off + (size_t)N * HID * 4);

    int eb = (E + 255) / 256;
    hipMemsetAsync(deg, 0, (size_t)2 * N * 4, stream);  // deg + fill
    convert_count<<<eb, 256, 0, stream>>>(eid, E, src, dst, deg);
    compute_dinv<<<(N + 255) / 256, 256, 0, stream>>>(deg, dinv, N);
    scan_blk_sum<<<NB1, 256, 0, stream>>>(deg, N, bsum);
    scan_offsets<<<1, 256, 0, stream>>>(bsum, NB1, rowp, N, E);
    scan_final<<<NB1, 256, 0, stream>>>(deg, N, bsum, rowp);
    scatter_csr<<<eb, 256, 0, stream>>>(src, dst, E, rowp, fill, csr);

    split_w<<<(IN_DIM * 128 + 255) / 256, 256, 0, stream>>>(W1, IN_DIM, W1hT, W1lT);
    split_w<<<(HID * 128 + 255) / 256, 256, 0, stream>>>(W2, HID, W2hT, W2lT);

    int gb = (N + 63) / 64;
    gemm_mfma<IN_DIM><<<gb, 256, 0, stream>>>(x, W1hT, W1lT, bufA, N);
    aggregate2<<<(N + 3) / 4, 256, 0, stream>>>(bufA, rowp, csr, dinv, b1, bufB, N);
    gemm_mfma<HID><<<gb, 256, 0, stream>>>(bufB, W2hT, W2lT, bufA, N);
    aggregate2<<<(N + 3) / 4, 256, 0, stream>>>(bufA, rowp, csr, dinv, b2, bufB, N);
    fc_out<<<(N + 7) / 8, 256, 0, stream>>>(bufB, Wfc, bfc, out, N);
}

// Round 6
// 392.894 us; speedup vs baseline: 2.0581x; 1.4140x over previous
//
#include <hip/hip_runtime.h>
#include <hip/hip_bf16.h>
#include <hip/hip_fp16.h>

#define N_NODES 50000
#define IN_DIM 768
#define HID 128
#define NCLS 32

typedef __attribute__((ext_vector_type(8))) short bf16x8;
typedef __attribute__((ext_vector_type(4))) float f32x4;
typedef __attribute__((ext_vector_type(4))) unsigned short u16x4;

__device__ inline void split_bf16(float x, unsigned short& hi, unsigned short& lo) {
    unsigned int u = __float_as_uint(x);
    hi = (unsigned short)(u >> 16);
    float r = x - __uint_as_float(u & 0xFFFF0000u);
    lo = (unsigned short)(__float_as_uint(r) >> 16);
}

// ---------------- edge conversion + degree count (int32 or int64 input) -------
__global__ void convert_count(const int* __restrict__ raw, int E,
                              int* __restrict__ src, int* __restrict__ dst,
                              int* __restrict__ deg) {
    bool is64 = (raw[1] == 0 && raw[3] == 0 && raw[5] == 0 && raw[7] == 0);
    int e = blockIdx.x * blockDim.x + threadIdx.x;
    if (e < E) {
        int s, d;
        if (is64) { s = raw[2 * e]; d = raw[2 * (E + e)]; }
        else      { s = raw[e];     d = raw[E + e]; }
        src[e] = s; dst[e] = d;
        atomicAdd(&deg[d], 1);
    }
}

__global__ void compute_dinv(const int* __restrict__ deg, float* __restrict__ dinv, int n) {
    int i = blockIdx.x * blockDim.x + threadIdx.x;
    if (i < n) dinv[i] = rsqrtf((float)(deg[i] + 1));  // +1 = self-loop
}

// ---------------- hierarchical exclusive scan (3 kernels) --------------------
__global__ __launch_bounds__(256) void scan_blk_sum(const int* __restrict__ cnt, int n,
                                                    int* __restrict__ bsum) {
    __shared__ int sm[256];
    int gid = blockIdx.x * 256 + threadIdx.x;
    sm[threadIdx.x] = (gid < n) ? cnt[gid] : 0;
    __syncthreads();
    for (int o = 128; o > 0; o >>= 1) {
        if (threadIdx.x < o) sm[threadIdx.x] += sm[threadIdx.x + o];
        __syncthreads();
    }
    if (threadIdx.x == 0) bsum[blockIdx.x] = sm[0];
}

__global__ __launch_bounds__(256) void scan_offsets(int* __restrict__ bsum, int nb,
                                                    int* __restrict__ rowp, int n, int Etot) {
    __shared__ int sm[256];
    int t = threadIdx.x;
    sm[t] = (t < nb) ? bsum[t] : 0;
    __syncthreads();
    for (int o = 1; o < 256; o <<= 1) {
        int v = (t >= o) ? sm[t - o] : 0;
        __syncthreads();
        sm[t] += v;
        __syncthreads();
    }
    if (t < nb) bsum[t] = (t == 0) ? 0 : sm[t - 1];
    if (t == 0) rowp[n] = Etot;
}

__global__ __launch_bounds__(256) void scan_final(const int* __restrict__ cnt, int n,
                                                  const int* __restrict__ bsum,
                                                  int* __restrict__ rowp) {
    __shared__ int sm[256];
    int t = threadIdx.x;
    int gid = blockIdx.x * 256 + t;
    int v = (gid < n) ? cnt[gid] : 0;
    sm[t] = v;
    __syncthreads();
    for (int o = 1; o < 256; o <<= 1) {
        int u = (t >= o) ? sm[t - o] : 0;
        __syncthreads();
        sm[t] += u;
        __syncthreads();
    }
    if (gid < n) rowp[gid] = bsum[blockIdx.x] + sm[t] - v;  // exclusive
}

__global__ void scatter_csr(const int* __restrict__ src, const int* __restrict__ dst, int E,
                            const int* __restrict__ row_ptr, int* __restrict__ fill,
                            int* __restrict__ csr_src) {
    int e = blockIdx.x * blockDim.x + threadIdx.x;
    if (e < E) {
        int d = dst[e];
        int pos = row_ptr[d] + atomicAdd(&fill[d], 1);
        csr_src[pos] = src[e];
    }
}

// ---------------- weight pack: W[K][128] f32 -> fragment-order split bf16 -----
// ph[((t*8 + c0)*64 + l)*8 + j] = hi(W[t*32 + (l>>4)*8 + j][c0*16 + (l&15)])
// -> in GEMM, a wave's B fragment load is 16B/lane fully coalesced.
__global__ void pack_w(const float* __restrict__ W, int K,
                       unsigned short* __restrict__ ph, unsigned short* __restrict__ pl) {
    int gid = blockIdx.x * 256 + threadIdx.x;
    int total = (K / 32) * 8 * 64;
    if (gid >= total) return;
    int l = gid & 63;
    int c0 = (gid >> 6) & 7;
    int t = gid >> 9;
    int col = c0 * 16 + (l & 15);
    int k0 = t * 32 + ((l >> 4) << 3);
    size_t base = (size_t)gid * 8;
#pragma unroll
    for (int j = 0; j < 8; ++j) {
        unsigned short h, lo;
        split_bf16(W[(size_t)(k0 + j) * 128 + col], h, lo);
        ph[base + j] = h;
        pl[base + j] = lo;
    }
}

// ---------------- split-bf16 MFMA GEMM: Chalf[M,128] = A[M,K] @ B[K,128] -----
// A f32 staged->LDS (reg double-buffered); B packed fragment-order in global.
// Epilogue writes fp16 table only (consumed by aggregate3).
template <int K>
__global__ __launch_bounds__(256) void gemm_mfma2(const float* __restrict__ A,
                                                  const unsigned short* __restrict__ Bph,
                                                  const unsigned short* __restrict__ Bpl,
                                                  __half* __restrict__ Chalf, int M) {
    __shared__ unsigned short Ah[64][40];  // 32 + 8 pad
    __shared__ unsigned short Al[64][40];
    int tid = threadIdx.x;
    int wid = tid >> 6, lane = tid & 63;
    int wr = wid >> 1, wc = wid & 1;      // wave grid 2x2
    int row0 = blockIdx.x * 64;
    int lrow = lane & 15, lk = (lane >> 4) * 8;
    const int T = K / 32;

    // staging address (each thread: 2 float4 = 8 floats of the 64x32 tile)
    int sidx0 = tid, sidx1 = 256 + tid;
    int sr0 = sidx0 >> 3, sc0 = (sidx0 & 7) * 4;
    int sr1 = sidx1 >> 3, sc1 = (sidx1 & 7) * 4;
    bool v0 = (row0 + sr0) < M, v1 = (row0 + sr1) < M;
    const float* a0 = &A[(size_t)(row0 + sr0) * K + sc0];
    const float* a1 = &A[(size_t)(row0 + sr1) * K + sc1];

    float4 pre0 = make_float4(0.f, 0.f, 0.f, 0.f), pre1 = pre0;
    if (v0) pre0 = *(const float4*)a0;
    if (v1) pre1 = *(const float4*)a1;

    f32x4 acc[2][4] = {};
    for (int t = 0; t < T; ++t) {
        // split staged regs -> LDS
        u16x4 h, lo;
        split_bf16(pre0.x, ((unsigned short*)&h)[0], ((unsigned short*)&lo)[0]);
        split_bf16(pre0.y, ((unsigned short*)&h)[1], ((unsigned short*)&lo)[1]);
        split_bf16(pre0.z, ((unsigned short*)&h)[2], ((unsigned short*)&lo)[2]);
        split_bf16(pre0.w, ((unsigned short*)&h)[3], ((unsigned short*)&lo)[3]);
        *(u16x4*)&Ah[sr0][sc0] = h;
        *(u16x4*)&Al[sr0][sc0] = lo;
        split_bf16(pre1.x, ((unsigned short*)&h)[0], ((unsigned short*)&lo)[0]);
        split_bf16(pre1.y, ((unsigned short*)&h)[1], ((unsigned short*)&lo)[1]);
        split_bf16(pre1.z, ((unsigned short*)&h)[2], ((unsigned short*)&lo)[2]);
        split_bf16(pre1.w, ((unsigned short*)&h)[3], ((unsigned short*)&lo)[3]);
        *(u16x4*)&Ah[sr1][sc1] = h;
        *(u16x4*)&Al[sr1][sc1] = lo;
        __syncthreads();
        // prefetch next A tile into regs (overlaps with frag reads + MFMA)
        if (t + 1 < T) {
            pre0 = make_float4(0.f, 0.f, 0.f, 0.f); pre1 = pre0;
            if (v0) pre0 = *(const float4*)(a0 + (t + 1) * 32);
            if (v1) pre1 = *(const float4*)(a1 + (t + 1) * 32);
        }
        // A fragments from LDS
        bf16x8 ah[2], al[2];
#pragma unroll
        for (int m = 0; m < 2; ++m) {
            int r = wr * 32 + m * 16 + lrow;
            ah[m] = *(const bf16x8*)&Ah[r][lk];
            al[m] = *(const bf16x8*)&Al[r][lk];
        }
        // B fragments: packed, coalesced (16B/lane contiguous)
        bf16x8 bh[4], bl[4];
#pragma unroll
        for (int n = 0; n < 4; ++n) {
            size_t boff = ((size_t)(t * 8 + wc * 4 + n) * 64 + lane) * 8;
            bh[n] = *(const bf16x8*)&Bph[boff];
            bl[n] = *(const bf16x8*)&Bpl[boff];
        }
#pragma unroll
        for (int m = 0; m < 2; ++m)
#pragma unroll
            for (int n = 0; n < 4; ++n) {
                acc[m][n] = __builtin_amdgcn_mfma_f32_16x16x32_bf16(ah[m], bh[n], acc[m][n], 0, 0, 0);
                acc[m][n] = __builtin_amdgcn_mfma_f32_16x16x32_bf16(al[m], bh[n], acc[m][n], 0, 0, 0);
                acc[m][n] = __builtin_amdgcn_mfma_f32_16x16x32_bf16(ah[m], bl[n], acc[m][n], 0, 0, 0);
            }
        __syncthreads();
    }
    // epilogue: fp16 table only. C/D layout col=lane&15, row=(lane>>4)*4+j
#pragma unroll
    for (int m = 0; m < 2; ++m) {
        int rbase = row0 + wr * 32 + m * 16 + (lane >> 4) * 4;
#pragma unroll
        for (int n = 0; n < 4; ++n) {
            int col = wc * 64 + n * 16 + lrow;
#pragma unroll
            for (int j = 0; j < 4; ++j) {
                int r = rbase + j;
                if (r < M) Chalf[(size_t)r * 128 + col] = __float2half(acc[m][n][j]);
            }
        }
    }
}

// ---------------- aggregation: wave-per-node, fp16 gather, unroll-8 ----------
__global__ __launch_bounds__(256) void aggregate3(const __half* __restrict__ ht,
                                                  const int* __restrict__ rowp,
                                                  const int* __restrict__ csr,
                                                  const float* __restrict__ dinv,
                                                  const float* __restrict__ bias,
                                                  float* __restrict__ out, int n) {
    int wid = threadIdx.x >> 6, lane = threadIdx.x & 63;
    int i = blockIdx.x * 4 + wid;
    if (i >= n) return;
    const __half2* h2 = (const __half2*)ht;  // [n][64] half2
    float di = dinv[i];
    float2 self = __half22float2(h2[(size_t)i * 64 + lane]);
    float2 acc;
    acc.x = di * di * self.x;
    acc.y = di * di * self.y;
    int b = rowp[i], e = rowp[i + 1];
    int p = b;
    for (; p + 8 <= e; p += 8) {
        int s[8]; float2 v[8]; float nn[8];
#pragma unroll
        for (int q = 0; q < 8; ++q) s[q] = csr[p + q];
#pragma unroll
        for (int q = 0; q < 8; ++q) v[q] = __half22float2(h2[(size_t)s[q] * 64 + lane]);
#pragma unroll
        for (int q = 0; q < 8; ++q) nn[q] = dinv[s[q]] * di;
#pragma unroll
        for (int q = 0; q < 8; ++q) { acc.x += nn[q] * v[q].x; acc.y += nn[q] * v[q].y; }
    }
    for (; p < e; ++p) {
        int s = csr[p];
        float nn = dinv[s] * di;
        float2 v = __half22float2(h2[(size_t)s * 64 + lane]);
        acc.x += nn * v.x;
        acc.y += nn * v.y;
    }
    float2 bb = ((const float2*)bias)[lane];
    float2 o;
    o.x = fmaxf(acc.x + bb.x, 0.f);
    o.y = fmaxf(acc.y + bb.y, 0.f);
    ((float2*)out)[(size_t)i * 64 + lane] = o;
}

// ---------------- final FC: out[N,32] = h[N,128] @ Wfc[128,32] + bfc ---------
__global__ __launch_bounds__(256) void fc_out(const float* __restrict__ h,
                                              const float* __restrict__ W,
                                              const float* __restrict__ b,
                                              float* __restrict__ out, int n) {
    __shared__ float Ws[HID * NCLS];
    __shared__ float Hs[8][HID];
    int tid = threadIdx.x;
#pragma unroll
    for (int l = 0; l < 16; ++l) Ws[l * 256 + tid] = W[l * 256 + tid];
    int row0 = blockIdx.x * 8;
#pragma unroll
    for (int l = 0; l < 4; ++l) {
        int idx = l * 256 + tid;
        int r = idx >> 7, c = idx & 127;
        int gr = row0 + r;
        Hs[r][c] = (gr < n) ? h[(size_t)gr * HID + c] : 0.f;
    }
    __syncthreads();
    int r = tid >> 5, c = tid & 31;
    float acc = b[c];
#pragma unroll
    for (int k = 0; k < HID; ++k) acc += Hs[r][k] * Ws[k * NCLS + c];
    int gr = row0 + r;
    if (gr < n) out[(size_t)gr * NCLS + c] = acc;
}

extern "C" void kernel_launch(void* const* d_in, const int* in_sizes, int n_in,
                              void* d_out, int out_size, void* d_ws, size_t ws_size,
                              hipStream_t stream) {
    const float* x   = (const float*)d_in[0];
    const int*   eid = (const int*)d_in[1];
    const float* W1  = (const float*)d_in[2];
    const float* b1  = (const float*)d_in[3];
    const float* W2  = (const float*)d_in[4];
    const float* b2  = (const float*)d_in[5];
    const float* Wfc = (const float*)d_in[6];
    const float* bfc = (const float*)d_in[7];
    float* out = (float*)d_out;

    const int N = N_NODES;
    const int E = in_sizes[1] / 2;
    const int NB1 = (N + 255) / 256;

    auto align = [](size_t v) { return (v + 255) & ~(size_t)255; };
    char* w = (char*)d_ws;
    size_t off = 0;
    int* src = (int*)(w + off);            off = align(off + (size_t)E * 4);
    int* dst = (int*)(w + off);            off = align(off + (size_t)E * 4);
    int* deg = (int*)(w + off);            off += (size_t)N * 4;  // deg+fill contiguous
    int* fill = (int*)(w + off);           off = align(off + (size_t)N * 4);
    int* rowp = (int*)(w + off);           off = align(off + (size_t)(N + 1) * 4);
    float* dinv = (float*)(w + off);       off = align(off + (size_t)N * 4);
    int* csr = (int*)(w + off);            off = align(off + (size_t)E * 4);
    int* bsum = (int*)(w + off);           off = align(off + (size_t)NB1 * 4);
    unsigned short* W1ph = (unsigned short*)(w + off); off = align(off + (size_t)128 * IN_DIM * 2);
    unsigned short* W1pl = (unsigned short*)(w + off); off = align(off + (size_t)128 * IN_DIM * 2);
    unsigned short* W2ph = (unsigned short*)(w + off); off = align(off + (size_t)128 * HID * 2);
    unsigned short* W2pl = (unsigned short*)(w + off); off = align(off + (size_t)128 * HID * 2);
    __half* h1 = (__half*)(w + off);       off = align(off + (size_t)N * HID * 2);
    __half* h2t = (__half*)(w + off);      off = align(off + (size_t)N * HID * 2);
    float* bufA = (float*)(w + off);       off = align(off + (size_t)N * HID * 4);
    float* bufB = (float*)(w + off);       off = align(off + (size_t)N * HID * 4);

    int eb = (E + 255) / 256;
    hipMemsetAsync(deg, 0, (size_t)2 * N * 4, stream);  // deg + fill
    convert_count<<<eb, 256, 0, stream>>>(eid, E, src, dst, deg);
    compute_dinv<<<(N + 255) / 256, 256, 0, stream>>>(deg, dinv, N);
    scan_blk_sum<<<NB1, 256, 0, stream>>>(deg, N, bsum);
    scan_offsets<<<1, 256, 0, stream>>>(bsum, NB1, rowp, N, E);
    scan_final<<<NB1, 256, 0, stream>>>(deg, N, bsum, rowp);
    scatter_csr<<<eb, 256, 0, stream>>>(src, dst, E, rowp, fill, csr);

    pack_w<<<((IN_DIM / 32) * 8 * 64 + 255) / 256, 256, 0, stream>>>(W1, IN_DIM, W1ph, W1pl);
    pack_w<<<((HID / 32) * 8 * 64 + 255) / 256, 256, 0, stream>>>(W2, HID, W2ph, W2pl);

    int gb = (N + 63) / 64;
    gemm_mfma2<IN_DIM><<<gb, 256, 0, stream>>>(x, W1ph, W1pl, h1, N);
    aggregate3<<<(N + 3) / 4, 256, 0, stream>>>(h1, rowp, csr, dinv, b1, bufA, N);
    gemm_mfma2<HID><<<gb, 256, 0, stream>>>(bufA, W2ph, W2pl, h2t, N);
    aggregate3<<<(N + 3) / 4, 256, 0, stream>>>(h2t, rowp, csr, dinv, b2, bufB, N);
    fc_out<<<(N + 7) / 8, 256, 0, stream>>>(bufB, Wfc, bfc, out, N);
}